// Round 6
// baseline (455.109 us; speedup 1.0000x reference)
//
#include <hip/hip_runtime.h>
#include <hip/hip_cooperative_groups.h>

namespace cg = cooperative_groups;

// Problem constants (fixed by setup_inputs)
#define NNODES 16384      // B*n = 8*2048
#define KEDGE  16
#define EPS    1e-5f
#define NBLK   512        // cooperative grid: 32 nodes/block, needs only 2 blocks/CU
                          // (capacity computes >=4/CU -> 2x margin; round-5's exact
                          //  1024-block fit was rejected by the runtime)

// Workspace layout (floats) — identical to round 4 so the fallback path works.
// Cooperative path uses part1/part2 (first 2048 rows) + st1/st2 only.
#define Y1_OFF  0
#define T2_OFF  (NNODES*64)             // y1: 16384*64     (fallback only)
#define P1_OFF  (T2_OFF + NNODES*128)   // t2: 16384*128    (fallback only)
#define P2_OFF  (P1_OFF + 4096*128)     // part1: <=4096 x 128
#define ST1_OFF (P2_OFF + 4096*256)     // part2: <=4096 x 256
#define ST2_OFF (ST1_OFF + 128)

// ===========================================================================
// PRIMARY: one cooperative kernel, 5 phases separated by grid syncs.
//   A : edge aggregation + 390x64 GEMM (2 batches of 4 nodes/wave) -> acc[8]
//   R1: 128 blocks each own one BN1 stat column (atomic-free, deterministic)
//   B : bn1+relu -> dual 64x128 GEMM -> a0/a1[8] (t2 rows stay in registers)
//   R2: 256 blocks each own one BN2 stat column
//   C : bn2+relu -> out straight from registers
// ===========================================================================
__global__ __launch_bounds__(256, 4) void k_all(
    const float* __restrict__ x, const float* __restrict__ p,
    const int* __restrict__ sid, const int* __restrict__ tid,
    const float* __restrict__ W, const float* __restrict__ bias,
    const float* __restrict__ g1, const float* __restrict__ b1,
    const float* __restrict__ W1, const float* __restrict__ bias1,
    const float* __restrict__ W2, const float* __restrict__ bias2,
    const float* __restrict__ g2, const float* __restrict__ b2,
    float* __restrict__ part1, float* __restrict__ part2,
    float* __restrict__ st1, float* __restrict__ st2,
    float* __restrict__ out)
{
    cg::grid_group grid = cg::this_grid();
    __shared__ float Ash[16][392];    // wave-private 4 rows/wave, reused per batch

    const int lane = threadIdx.x & 63;
    const int wv   = threadIdx.x >> 6;
    const int tw8  = blockIdx.x * 32 + wv * 8;   // first of this wave's 8 nodes
    const int row  = blockIdx.x * 4 + wv;        // partial row (2048 total)
    const int rb   = wv * 4;

    float bv[6];
    #pragma unroll
    for (int sx = 0; sx < 6; ++sx) bv[sx] = bias[sx*64 + lane];

    float xv[8], acc[8];
    float sloc = 0.f, qloc = 0.f;

    // ======== phase A: two batches of 4 nodes =========
    #pragma unroll
    for (int b = 0; b < 2; ++b) {
        const int t1  = tw8 + b*4 + (lane >> 4);          // lane=(node,edge)
        const int s   = sid[t1 * KEDGE + (lane & 15)];    // coalesced
        const int tn1 = tid[t1 * KEDGE];
        const float ptx = p[tn1*3+0], pty = p[tn1*3+1], ptz = p[tn1*3+2];
        const float dx = p[s*3+0] - ptx;
        const float dy = p[s*3+1] - pty;
        const float dz = p[s*3+2] - ptz;
        float pdv = fmaxf(sqrtf(dx*dx + dy*dy + dz*dz), 1e-16f);

        float prm = pdv;                                  // max over 16-group
        prm = fmaxf(prm, __shfl_xor(prm, 1));
        prm = fmaxf(prm, __shfl_xor(prm, 2));
        prm = fmaxf(prm, __shfl_xor(prm, 4));
        prm = fmaxf(prm, __shfl_xor(prm, 8));
        prm *= 1.1f;

        float wgt = (prm - pdv) * (prm - pdv);
        float wsum = wgt;
        wsum += __shfl_xor(wsum, 1);
        wsum += __shfl_xor(wsum, 2);
        wsum += __shfl_xor(wsum, 4);
        wsum += __shfl_xor(wsum, 8);
        wgt /= wsum;

        const float invd = 1.f / pdv;
        const float c0 = __cosf(dx * invd);  // |arg|<=1: no range reduction
        const float c1 = __cosf(dy * invd);
        const float c2 = __cosf(dz * invd);
        const float w0 = wgt * c0 * c0;
        const float w1 = wgt * c1 * c1;
        const float w2 = wgt * c2 * c2;
        const int flags = (dx > 0.f ? 1 : 0) | (dy > 0.f ? 2 : 0) | (dz > 0.f ? 4 : 0);

        #pragma unroll
        for (int i = 0; i < 4; ++i) {
            const int tn = __shfl(tn1, i * 16);
            const float xt = x[tn*64 + lane];             // lane = channel here
            xv[b*4 + i] = xt;
            float A0=0,A1=0,A2=0,A3=0,A4=0,A5=0;
            float B0=0,B1=0,B2=0,B3=0,B4=0,B5=0;
            #pragma unroll
            for (int j = 0; j < KEDGE; ++j) {
                const int src = i*16 + j;
                const int   sv = __shfl(s,  src);
                const float q0 = __shfl(w0, src);
                const float q1 = __shfl(w1, src);
                const float q2 = __shfl(w2, src);
                const int   f  = __builtin_amdgcn_readfirstlane(__shfl(flags, src));
                const float e  = x[sv*64 + lane] - xt;
                if (f & 1) { A1 += q0*e; B1 += q0; } else { A0 += q0*e; B0 += q0; }
                if (f & 2) { A3 += q1*e; B3 += q1; } else { A2 += q1*e; B2 += q1; }
                if (f & 4) { A5 += q2*e; B5 += q2; } else { A4 += q2*e; B4 += q2; }
            }
            const int r = rb + i;
            Ash[r][0*64+lane] = A0; Ash[r][1*64+lane] = A1; Ash[r][2*64+lane] = A2;
            Ash[r][3*64+lane] = A3; Ash[r][4*64+lane] = A4; Ash[r][5*64+lane] = A5;
            if (lane == 0) {        // B's are lane-invariant
                Ash[r][384] = B0; Ash[r][385] = B1; Ash[r][386] = B2;
                Ash[r][387] = B3; Ash[r][388] = B4; Ash[r][389] = B5;
            }
        }
        // Ash rows wave-private; same-wave LDS ordering (lgkmcnt) suffices.

        // ---- 4-row GEMM for this batch: y = A @ [lins_W; lins_b]
        const float* Wp = W + lane;
        float cc[4] = {0,0,0,0};
        #pragma unroll 2
        for (int k = 0; k < 384; k += 4) {
            const float4 a0v = *(const float4*)&Ash[rb+0][k];  // uniform -> bcast
            const float4 a1v = *(const float4*)&Ash[rb+1][k];
            const float4 a2v = *(const float4*)&Ash[rb+2][k];
            const float4 a3v = *(const float4*)&Ash[rb+3][k];
            const float wk0 = Wp[(k+0)*64];
            const float wk1 = Wp[(k+1)*64];
            const float wk2 = Wp[(k+2)*64];
            const float wk3 = Wp[(k+3)*64];
            cc[0] += a0v.x*wk0 + a0v.y*wk1 + a0v.z*wk2 + a0v.w*wk3;
            cc[1] += a1v.x*wk0 + a1v.y*wk1 + a1v.z*wk2 + a1v.w*wk3;
            cc[2] += a2v.x*wk0 + a2v.y*wk1 + a2v.z*wk2 + a2v.w*wk3;
            cc[3] += a3v.x*wk0 + a3v.y*wk1 + a3v.z*wk2 + a3v.w*wk3;
        }
        #pragma unroll
        for (int i = 0; i < 4; ++i) {
            float a = cc[i];
            #pragma unroll
            for (int sx = 0; sx < 6; ++sx) a += Ash[rb+i][384+sx] * bv[sx];
            acc[b*4 + i] = a;                 // y1 stays in registers
            sloc += a; qloc += a*a;
        }
    }
    part1[row*128 + lane]      = sloc;        // per-wave BN1 partial row
    part1[row*128 + 64 + lane] = qloc;

    grid.sync();

    // ======== R1: 128 blocks each reduce one column of part1 (2048 rows)
    if (blockIdx.x < 128) {
        float* red = (float*)Ash;
        const float* pp = part1 + blockIdx.x;
        float sum = 0.f;
        #pragma unroll
        for (int i = 0; i < 8; ++i)
            sum += pp[(size_t)(threadIdx.x + i*256) * 128];
        red[threadIdx.x] = sum;
        __syncthreads();
        if (threadIdx.x < 128) red[threadIdx.x] += red[threadIdx.x + 128];
        __syncthreads();
        if (threadIdx.x < 64) {
            float v = red[threadIdx.x] + red[threadIdx.x + 64];
            v += __shfl_down(v, 32);
            v += __shfl_down(v, 16);
            v += __shfl_down(v, 8);
            v += __shfl_down(v, 4);
            v += __shfl_down(v, 2);
            v += __shfl_down(v, 1);
            if (threadIdx.x == 0) st1[blockIdx.x] = v;
        }
    }

    grid.sync();

    // ======== phase B: bn1+relu, then t2 = x@W1 + z@W2 + biases (registers)
    const float n_inv = 1.f / NNODES;
    {
        const float mu  = st1[lane] * n_inv;
        const float var = st1[64 + lane] * n_inv - mu*mu;
        const float sc  = rsqrtf(var + EPS) * g1[lane];
        const float sh  = b1[lane] - mu*sc;
        #pragma unroll
        for (int i = 0; i < 8; ++i)
            acc[i] = fmaxf(acc[i]*sc + sh, 0.f);      // acc becomes z
    }
    float a0[8] = {0,0,0,0,0,0,0,0}, a1[8] = {0,0,0,0,0,0,0,0};
    #pragma unroll 4
    for (int k = 0; k < 64; ++k) {
        const float w1a = W1[k*128 + lane],      w1b = W1[k*128 + 64 + lane];
        const float w2a = W2[k*128 + lane],      w2b = W2[k*128 + 64 + lane];
        #pragma unroll
        for (int i = 0; i < 8; ++i) {
            const float xk = __shfl(xv[i],  k);
            const float zk = __shfl(acc[i], k);
            a0[i] += xk*w1a + zk*w2a;
            a1[i] += xk*w1b + zk*w2b;
        }
    }
    {
        const float bb0 = bias1[lane]      + bias2[lane];
        const float bb1 = bias1[64 + lane] + bias2[64 + lane];
        float s0=0,q0=0,s1=0,q1=0;
        #pragma unroll
        for (int i = 0; i < 8; ++i) {
            a0[i] += bb0; a1[i] += bb1;               // t2 stays in registers
            s0 += a0[i]; q0 += a0[i]*a0[i];
            s1 += a1[i]; q1 += a1[i]*a1[i];
        }
        float* prw = part2 + (size_t)row * 256;
        prw[lane]       = s0;   // sum,   cols 0..63
        prw[64 + lane]  = s1;   // sum,   cols 64..127
        prw[128 + lane] = q0;   // sumsq, cols 0..63
        prw[192 + lane] = q1;   // sumsq, cols 64..127
    }

    grid.sync();

    // ======== R2: 256 blocks each reduce one column of part2 (2048 rows)
    if (blockIdx.x < 256) {
        float* red = (float*)Ash;
        const float* pp = part2 + blockIdx.x;
        float sum = 0.f;
        #pragma unroll
        for (int i = 0; i < 8; ++i)
            sum += pp[(size_t)(threadIdx.x + i*256) * 256];
        red[threadIdx.x] = sum;
        __syncthreads();
        if (threadIdx.x < 128) red[threadIdx.x] += red[threadIdx.x + 128];
        __syncthreads();
        if (threadIdx.x < 64) {
            float v = red[threadIdx.x] + red[threadIdx.x + 64];
            v += __shfl_down(v, 32);
            v += __shfl_down(v, 16);
            v += __shfl_down(v, 8);
            v += __shfl_down(v, 4);
            v += __shfl_down(v, 2);
            v += __shfl_down(v, 1);
            if (threadIdx.x == 0) st2[blockIdx.x] = v;
        }
    }

    grid.sync();

    // ======== phase C: bn2+relu straight from registers -> out
    {
        const float mua  = st2[lane] * n_inv;
        const float vara = st2[128 + lane] * n_inv - mua*mua;
        const float sca  = rsqrtf(vara + EPS) * g2[lane];
        const float sha  = b2[lane] - mua*sca;
        const float mub  = st2[64 + lane] * n_inv;
        const float varb = st2[192 + lane] * n_inv - mub*mub;
        const float scb  = rsqrtf(varb + EPS) * g2[64 + lane];
        const float shb  = b2[64 + lane] - mub*scb;
        #pragma unroll
        for (int i = 0; i < 8; ++i) {
            out[(size_t)(tw8 + i)*128 + lane]      = fmaxf(a0[i]*sca + sha, 0.f);
            out[(size_t)(tw8 + i)*128 + 64 + lane] = fmaxf(a1[i]*scb + shb, 0.f);
        }
    }
}

// ===========================================================================
// FALLBACK: round-4 five-dispatch pipeline (known-good, 172 us), used only if
// the cooperative launch is rejected. Deterministic per call -> graph-safe.
// ===========================================================================
__global__ __launch_bounds__(256) void k_node(
    const float* __restrict__ x, const float* __restrict__ p,
    const int* __restrict__ sid, const int* __restrict__ tid,
    const float* __restrict__ W, const float* __restrict__ bias,
    float* __restrict__ y1, float* __restrict__ part1)
{
    __shared__ float Ash[16][392];

    const int lane = threadIdx.x & 63;
    const int wv   = threadIdx.x >> 6;
    const int tw   = blockIdx.x * 16 + wv * 4;

    const int ii = lane >> 4;
    const int t1 = tw + ii;
    const int s  = sid[t1 * KEDGE + (lane & 15)];
    const int tn1 = tid[t1 * KEDGE];
    const float ptx = p[tn1*3+0], pty = p[tn1*3+1], ptz = p[tn1*3+2];
    const float dx = p[s*3+0] - ptx;
    const float dy = p[s*3+1] - pty;
    const float dz = p[s*3+2] - ptz;
    float pd = fmaxf(sqrtf(dx*dx + dy*dy + dz*dz), 1e-16f);

    float pr = pd;
    pr = fmaxf(pr, __shfl_xor(pr, 1));
    pr = fmaxf(pr, __shfl_xor(pr, 2));
    pr = fmaxf(pr, __shfl_xor(pr, 4));
    pr = fmaxf(pr, __shfl_xor(pr, 8));
    pr *= 1.1f;

    float w = (pr - pd) * (pr - pd);
    float wsum = w;
    wsum += __shfl_xor(wsum, 1);
    wsum += __shfl_xor(wsum, 2);
    wsum += __shfl_xor(wsum, 4);
    wsum += __shfl_xor(wsum, 8);
    w /= wsum;

    const float invd = 1.f / pd;
    const float c0 = __cosf(dx * invd);
    const float c1 = __cosf(dy * invd);
    const float c2 = __cosf(dz * invd);
    const float w0 = w * c0 * c0;
    const float w1 = w * c1 * c1;
    const float w2 = w * c2 * c2;
    const int flags = (dx > 0.f ? 1 : 0) | (dy > 0.f ? 2 : 0) | (dz > 0.f ? 4 : 0);

    #pragma unroll
    for (int i = 0; i < 4; ++i) {
        const int tn = __shfl(tn1, i * 16);
        const float xt = x[tn*64 + lane];
        float A0=0,A1=0,A2=0,A3=0,A4=0,A5=0;
        float B0=0,B1=0,B2=0,B3=0,B4=0,B5=0;
        #pragma unroll
        for (int j = 0; j < KEDGE; ++j) {
            const int src = i*16 + j;
            const int   sv = __shfl(s,  src);
            const float q0 = __shfl(w0, src);
            const float q1 = __shfl(w1, src);
            const float q2 = __shfl(w2, src);
            const int   f  = __builtin_amdgcn_readfirstlane(__shfl(flags, src));
            const float e  = x[sv*64 + lane] - xt;
            if (f & 1) { A1 += q0*e; B1 += q0; } else { A0 += q0*e; B0 += q0; }
            if (f & 2) { A3 += q1*e; B3 += q1; } else { A2 += q1*e; B2 += q1; }
            if (f & 4) { A5 += q2*e; B5 += q2; } else { A4 += q2*e; B4 += q2; }
        }
        const int r = wv*4 + i;
        Ash[r][0*64+lane] = A0; Ash[r][1*64+lane] = A1; Ash[r][2*64+lane] = A2;
        Ash[r][3*64+lane] = A3; Ash[r][4*64+lane] = A4; Ash[r][5*64+lane] = A5;
        if (lane == 0) {
            Ash[r][384] = B0; Ash[r][385] = B1; Ash[r][386] = B2;
            Ash[r][387] = B3; Ash[r][388] = B4; Ash[r][389] = B5;
        }
    }

    const float* Wp = W + lane;
    const int rb = wv * 4;
    float acc[4] = {0,0,0,0};
    #pragma unroll 2
    for (int k = 0; k < 384; k += 4) {
        const float4 a0 = *(const float4*)&Ash[rb+0][k];
        const float4 a1 = *(const float4*)&Ash[rb+1][k];
        const float4 a2 = *(const float4*)&Ash[rb+2][k];
        const float4 a3 = *(const float4*)&Ash[rb+3][k];
        const float wk0 = Wp[(k+0)*64];
        const float wk1 = Wp[(k+1)*64];
        const float wk2 = Wp[(k+2)*64];
        const float wk3 = Wp[(k+3)*64];
        acc[0] += a0.x*wk0 + a0.y*wk1 + a0.z*wk2 + a0.w*wk3;
        acc[1] += a1.x*wk0 + a1.y*wk1 + a1.z*wk2 + a1.w*wk3;
        acc[2] += a2.x*wk0 + a2.y*wk1 + a2.z*wk2 + a2.w*wk3;
        acc[3] += a3.x*wk0 + a3.y*wk1 + a3.z*wk2 + a3.w*wk3;
    }
    float bv[6];
    #pragma unroll
    for (int sx = 0; sx < 6; ++sx) bv[sx] = bias[sx*64 + lane];

    float sloc = 0.f, qloc = 0.f;
    #pragma unroll
    for (int i = 0; i < 4; ++i) {
        float a = acc[i];
        #pragma unroll
        for (int sx = 0; sx < 6; ++sx) a += Ash[rb+i][384+sx] * bv[sx];
        y1[(tw+i)*64 + lane] = a;
        sloc += a; qloc += a*a;
    }
    const int row = blockIdx.x * 4 + wv;
    part1[row*128 + lane]      = sloc;
    part1[row*128 + 64 + lane] = qloc;
}

__global__ __launch_bounds__(256) void k_red1(
    const float* __restrict__ part, float* __restrict__ st)
{
    __shared__ float red[256];
    const int c = threadIdx.x & 127;
    const int h = threadIdx.x >> 7;
    const float* pp = part + ((size_t)blockIdx.x * 64 + h * 32) * 128 + c;
    float s = 0.f;
    #pragma unroll 8
    for (int b = 0; b < 32; ++b) s += pp[b*128];
    red[threadIdx.x] = s;
    __syncthreads();
    if (h == 0) atomicAdd(&st[c], red[c] + red[128 + c]);
}

__global__ __launch_bounds__(256) void k_fused2(
    const float* __restrict__ x, const int* __restrict__ tid,
    const float* __restrict__ y1, const float* __restrict__ stats1,
    const float* __restrict__ g1, const float* __restrict__ b1,
    const float* __restrict__ W1, const float* __restrict__ bias1,
    const float* __restrict__ W2, const float* __restrict__ bias2,
    float* __restrict__ t2, float* __restrict__ part2)
{
    const int lane = threadIdx.x & 63;
    const int wv   = threadIdx.x >> 6;
    const int r0   = (blockIdx.x * 4 + wv) * 4;

    const float mu  = stats1[lane] * (1.f / NNODES);
    const float var = stats1[64 + lane] * (1.f / NNODES) - mu*mu;
    const float sc  = rsqrtf(var + EPS) * g1[lane];
    const float sh  = b1[lane] - mu*sc;

    float xv[4], zv[4];
    #pragma unroll
    for (int i = 0; i < 4; ++i) {
        const int tn = tid[(r0 + i) * KEDGE];
        xv[i] = x[tn*64 + lane];
        const float yv = y1[(r0 + i)*64 + lane];
        zv[i] = fmaxf(yv*sc + sh, 0.f);
    }
    float a0[4] = {0,0,0,0}, a1[4] = {0,0,0,0};
    #pragma unroll 4
    for (int k = 0; k < 64; ++k) {
        const float w1a = W1[k*128 + lane],      w1b = W1[k*128 + 64 + lane];
        const float w2a = W2[k*128 + lane],      w2b = W2[k*128 + 64 + lane];
        #pragma unroll
        for (int i = 0; i < 4; ++i) {
            const float xk = __shfl(xv[i], k);
            const float zk = __shfl(zv[i], k);
            a0[i] += xk*w1a + zk*w2a;
            a1[i] += xk*w1b + zk*w2b;
        }
    }
    const float bb0 = bias1[lane]      + bias2[lane];
    const float bb1 = bias1[64 + lane] + bias2[64 + lane];
    float s0=0,q0=0,s1=0,q1=0;
    #pragma unroll
    for (int i = 0; i < 4; ++i) {
        const float v0 = a0[i] + bb0;
        const float v1 = a1[i] + bb1;
        t2[(size_t)(r0 + i)*128 + lane]      = v0;
        t2[(size_t)(r0 + i)*128 + 64 + lane] = v1;
        s0 += v0; q0 += v0*v0;
        s1 += v1; q1 += v1*v1;
    }
    float* pr = part2 + ((size_t)blockIdx.x * 4 + wv) * 256;
    pr[lane]       = s0;
    pr[64 + lane]  = s1;
    pr[128 + lane] = q0;
    pr[192 + lane] = q1;
}

__global__ __launch_bounds__(256) void k_red2(
    const float* __restrict__ part, float* __restrict__ st)
{
    const int c = threadIdx.x;
    const float* pp = part + (size_t)blockIdx.x * 64 * 256 + c;
    float s = 0.f;
    #pragma unroll 8
    for (int b = 0; b < 64; ++b) s += pp[b*256];
    atomicAdd(&st[c], s);
}

__global__ __launch_bounds__(256) void k_bn2(
    const float* __restrict__ t2, const float* __restrict__ stats,
    const float* __restrict__ g2, const float* __restrict__ b2,
    float* __restrict__ out)
{
    const int idx = blockIdx.x * 256 + threadIdx.x;
    const int c   = idx & 127;
    const float mu  = stats[c] * (1.f / NNODES);
    const float var = stats[128 + c] * (1.f / NNODES) - mu*mu;
    const float sc  = rsqrtf(var + EPS) * g2[c];
    const float sh  = b2[c] - mu*sc;
    const float v = t2[idx];
    out[idx] = fmaxf(v*sc + sh, 0.f);
}

extern "C" void kernel_launch(void* const* d_in, const int* in_sizes, int n_in,
                              void* d_out, int out_size, void* d_ws, size_t ws_size,
                              hipStream_t stream)
{
    const float* x     = (const float*)d_in[0];
    const float* p     = (const float*)d_in[1];
    const int*   sid   = (const int*)d_in[2];
    const int*   tid   = (const int*)d_in[3];
    // d_in[4] = B, d_in[5] = n (scalars, unused — constants hardcoded)
    const float* linsW = (const float*)d_in[6];
    const float* linsB = (const float*)d_in[7];
    const float* W1    = (const float*)d_in[8];
    const float* b1l   = (const float*)d_in[9];
    const float* W2    = (const float*)d_in[10];
    const float* b2l   = (const float*)d_in[11];
    const float* g1    = (const float*)d_in[12];
    const float* bb1   = (const float*)d_in[13];
    const float* g2    = (const float*)d_in[14];
    const float* bb2   = (const float*)d_in[15];

    float* ws    = (float*)d_ws;
    float* y1    = ws + Y1_OFF;
    float* t2    = ws + T2_OFF;
    float* part1 = ws + P1_OFF;
    float* part2 = ws + P2_OFF;
    float* st1   = ws + ST1_OFF;
    float* st2   = ws + ST2_OFF;
    float* outp  = (float*)d_out;

    void* args[] = {
        (void*)&x, (void*)&p, (void*)&sid, (void*)&tid,
        (void*)&linsW, (void*)&linsB,
        (void*)&g1, (void*)&bb1,
        (void*)&W1, (void*)&b1l, (void*)&W2, (void*)&b2l,
        (void*)&g2, (void*)&bb2,
        (void*)&part1, (void*)&part2, (void*)&st1, (void*)&st2,
        (void*)&outp
    };
    hipError_t rc = hipLaunchCooperativeKernel((const void*)k_all, dim3(NBLK),
                                               dim3(256), args, 0, stream);
    if (rc != hipSuccess) {
        // Round-4 fallback path (deterministic: rc is the same every call)
        hipMemsetAsync(st1, 0, (128 + 256) * sizeof(float), stream);
        k_node  <<<NNODES/16,        256, 0, stream>>>(x, p, sid, tid, linsW,
                                                       linsB, y1, part1);
        k_red1  <<<64,               256, 0, stream>>>(part1, st1);
        k_fused2<<<NNODES/16,        256, 0, stream>>>(x, tid, y1, st1, g1, bb1,
                                                       W1, b1l, W2, b2l, t2, part2);
        k_red2  <<<64,               256, 0, stream>>>(part2, st2);
        k_bn2   <<<(NNODES*128)/256, 256, 0, stream>>>(t2, st2, g2, bb2, outp);
    }
}

// Round 7
// 360.710 us; speedup vs baseline: 1.2617x; 1.2617x over previous
//
#include <hip/hip_runtime.h>

// Problem constants (fixed by setup_inputs)
#define NNODES 16384      // B*n = 8*2048
#define KEDGE  16
#define EPS    1e-5f
#define NBLK1  1024       // K1/K2 grid (16 nodes per block)

// Workspace layout (floats).
// Round-2 lesson: no dense-region atomics (TCC serializes ~1/cy per line).
// Round-6 lesson: cooperative grid.sync costs ~20us each + kills occupancy.
// Round-7: 3 dispatches; BN stats via "last block reduces" (threadfence +
// atomic counter, hipCUB-style) — fences give device-scope visibility
// across XCDs; reduction order fixed -> deterministic.
#define Y1_OFF  0
#define T2_OFF  (NNODES*64)              // y1: 16384*64
#define P1_OFF  (T2_OFF + NNODES*128)    // t2: 16384*128
#define P2_OFF  (P1_OFF + NBLK1*128)     // part1: 1024 x 128 (sum[64],sumsq[64])
#define ST1_OFF (P2_OFF + NBLK1*256)     // part2: 1024 x 256
#define ST2_OFF (ST1_OFF + 128)
#define CNT_OFF (ST2_OFF + 256)          // 2 ints (zeroed by memset each call)

// ---------------------------------------------------------------------------
// K1: edge aggregation + 390x64 GEMM + BN1 stats (block partials + last-block
// reduction). Block = 4 waves x 4 nodes/wave = 16 nodes.
// ---------------------------------------------------------------------------
__global__ __launch_bounds__(256) void k_node(
    const float* __restrict__ x, const float* __restrict__ p,
    const int* __restrict__ sid, const int* __restrict__ tid,
    const float* __restrict__ W, const float* __restrict__ bias,
    float* __restrict__ y1, float* __restrict__ part1,
    float* __restrict__ st1, int* __restrict__ cnt)
{
    __shared__ float Ash[16][392];     // 390 used/row; 392 keeps rows 16B-aligned
    __shared__ float redsh[4][128];
    __shared__ int amLast;

    const int lane = threadIdx.x & 63;
    const int wv   = threadIdx.x >> 6;
    const int tw   = blockIdx.x * 16 + wv * 4;   // first node of this wave

    // ---- phase 1: one edge per lane (node ii = lane>>4, edge jj = lane&15)
    const int ii = lane >> 4;
    const int t1 = tw + ii;
    const int s  = sid[t1 * KEDGE + (lane & 15)];     // coalesced
    const int tn1 = tid[t1 * KEDGE];
    const float ptx = p[tn1*3+0], pty = p[tn1*3+1], ptz = p[tn1*3+2];
    const float dx = p[s*3+0] - ptx;
    const float dy = p[s*3+1] - pty;
    const float dz = p[s*3+2] - ptz;
    float pd = fmaxf(sqrtf(dx*dx + dy*dy + dz*dz), 1e-16f);

    float pr = pd;                                     // max over the 16-group
    pr = fmaxf(pr, __shfl_xor(pr, 1));
    pr = fmaxf(pr, __shfl_xor(pr, 2));
    pr = fmaxf(pr, __shfl_xor(pr, 4));
    pr = fmaxf(pr, __shfl_xor(pr, 8));
    pr *= 1.1f;

    float w = (pr - pd) * (pr - pd);
    float wsum = w;
    wsum += __shfl_xor(wsum, 1);
    wsum += __shfl_xor(wsum, 2);
    wsum += __shfl_xor(wsum, 4);
    wsum += __shfl_xor(wsum, 8);
    w /= wsum;

    const float invd = 1.f / pd;
    const float c0 = __cosf(dx * invd);   // |arg|<=1: no range reduction needed
    const float c1 = __cosf(dy * invd);
    const float c2 = __cosf(dz * invd);
    const float w0 = w * c0 * c0;
    const float w1 = w * c1 * c1;
    const float w2 = w * c2 * c2;
    const int flags = (dx > 0.f ? 1 : 0) | (dy > 0.f ? 2 : 0) | (dz > 0.f ? 4 : 0);

    // ---- phase 2: per node, gather x rows and accumulate six A vectors + betas
    #pragma unroll
    for (int i = 0; i < 4; ++i) {
        const int tn = __shfl(tn1, i * 16);
        const float xt = x[tn*64 + lane];              // lane = channel here
        float A0=0,A1=0,A2=0,A3=0,A4=0,A5=0;
        float B0=0,B1=0,B2=0,B3=0,B4=0,B5=0;
        #pragma unroll
        for (int j = 0; j < KEDGE; ++j) {
            const int src = i*16 + j;
            const int   sv = __shfl(s,  src);
            const float q0 = __shfl(w0, src);
            const float q1 = __shfl(w1, src);
            const float q2 = __shfl(w2, src);
            const int   f  = __builtin_amdgcn_readfirstlane(__shfl(flags, src));
            const float e  = x[sv*64 + lane] - xt;
            if (f & 1) { A1 += q0*e; B1 += q0; } else { A0 += q0*e; B0 += q0; }
            if (f & 2) { A3 += q1*e; B3 += q1; } else { A2 += q1*e; B2 += q1; }
            if (f & 4) { A5 += q2*e; B5 += q2; } else { A4 += q2*e; B4 += q2; }
        }
        const int r = wv*4 + i;
        Ash[r][0*64+lane] = A0; Ash[r][1*64+lane] = A1; Ash[r][2*64+lane] = A2;
        Ash[r][3*64+lane] = A3; Ash[r][4*64+lane] = A4; Ash[r][5*64+lane] = A5;
        if (lane == 0) {       // B's are lane-invariant
            Ash[r][384] = B0; Ash[r][385] = B1; Ash[r][386] = B2;
            Ash[r][387] = B3; Ash[r][388] = B4; Ash[r][389] = B5;
        }
    }
    // Ash rows are wave-private; compiler's lgkmcnt wait suffices, no barrier.

    // ---- phase 3: 4-row GEMM  y = A @ [lins_W; lins_b]
    const float* Wp = W + lane;
    const int rb = wv * 4;
    float acc[4] = {0,0,0,0};
    #pragma unroll 2
    for (int k = 0; k < 384; k += 4) {
        const float4 a0 = *(const float4*)&Ash[rb+0][k];   // uniform addr -> bcast
        const float4 a1 = *(const float4*)&Ash[rb+1][k];
        const float4 a2 = *(const float4*)&Ash[rb+2][k];
        const float4 a3 = *(const float4*)&Ash[rb+3][k];
        const float wk0 = Wp[(k+0)*64];
        const float wk1 = Wp[(k+1)*64];
        const float wk2 = Wp[(k+2)*64];
        const float wk3 = Wp[(k+3)*64];
        acc[0] += a0.x*wk0 + a0.y*wk1 + a0.z*wk2 + a0.w*wk3;
        acc[1] += a1.x*wk0 + a1.y*wk1 + a1.z*wk2 + a1.w*wk3;
        acc[2] += a2.x*wk0 + a2.y*wk1 + a2.z*wk2 + a2.w*wk3;
        acc[3] += a3.x*wk0 + a3.y*wk1 + a3.z*wk2 + a3.w*wk3;
    }
    float bv[6];
    #pragma unroll
    for (int sx = 0; sx < 6; ++sx) bv[sx] = bias[sx*64 + lane];

    float sloc = 0.f, qloc = 0.f;
    #pragma unroll
    for (int i = 0; i < 4; ++i) {
        float a = acc[i];
        #pragma unroll
        for (int sx = 0; sx < 6; ++sx) a += Ash[rb+i][384+sx] * bv[sx];
        y1[(tw+i)*64 + lane] = a;
        sloc += a; qloc += a*a;
    }

    // ---- BN1 block partial (LDS combine, one 128-float row per block)
    redsh[wv][lane]      = sloc;
    redsh[wv][64 + lane] = qloc;
    __syncthreads();
    if (threadIdx.x < 128) {
        const int t = threadIdx.x;
        part1[blockIdx.x*128 + t] =
            redsh[0][t] + redsh[1][t] + redsh[2][t] + redsh[3][t];
    }
    // ---- last block reduces part1 -> st1 (threadfence+counter, hipCUB-style)
    __threadfence();                       // release: make part1 row visible
    __syncthreads();
    if (threadIdx.x == 0)
        amLast = (atomicAdd(cnt, 1) == (int)gridDim.x - 1);
    __syncthreads();
    if (amLast) {
        __threadfence();                   // acquire: see all blocks' part1
        const int c = threadIdx.x & 127;
        const int h = threadIdx.x >> 7;    // rows [0,512) / [512,1024)
        const float* pp = part1 + (size_t)h * 512 * 128 + c;
        float sum = 0.f;
        #pragma unroll 8
        for (int b = 0; b < 512; ++b) sum += pp[b*128];
        float* rs = (float*)Ash;
        rs[threadIdx.x] = sum;
        __syncthreads();
        if (h == 0) st1[c] = rs[c] + rs[128 + c];
    }
}

// ---------------------------------------------------------------------------
// K2: t2 = x@lin1_W + relu(bn1(y1))@lin2_W + biases, BN2 stats (block
// partials + last-block reduction). One wave = 4 rows; lane covers output
// cols {lane, lane+64}.
// ---------------------------------------------------------------------------
__global__ __launch_bounds__(256) void k_fused2(
    const float* __restrict__ x, const int* __restrict__ tid,
    const float* __restrict__ y1, const float* __restrict__ stats1,
    const float* __restrict__ g1, const float* __restrict__ b1,
    const float* __restrict__ W1, const float* __restrict__ bias1,
    const float* __restrict__ W2, const float* __restrict__ bias2,
    float* __restrict__ t2, float* __restrict__ part2,
    float* __restrict__ st2, int* __restrict__ cnt)
{
    __shared__ float redsh[4][256];
    __shared__ int amLast;

    const int lane = threadIdx.x & 63;
    const int wv   = threadIdx.x >> 6;
    const int r0   = (blockIdx.x * 4 + wv) * 4;

    const float mu  = stats1[lane] * (1.f / NNODES);
    const float var = stats1[64 + lane] * (1.f / NNODES) - mu*mu;
    const float sc  = rsqrtf(var + EPS) * g1[lane];
    const float sh  = b1[lane] - mu*sc;

    float xv[4], zv[4];
    #pragma unroll
    for (int i = 0; i < 4; ++i) {
        const int tn = tid[(r0 + i) * KEDGE];
        xv[i] = x[tn*64 + lane];
        const float yv = y1[(r0 + i)*64 + lane];
        zv[i] = fmaxf(yv*sc + sh, 0.f);
    }
    float a0[4] = {0,0,0,0}, a1[4] = {0,0,0,0};
    #pragma unroll 4
    for (int k = 0; k < 64; ++k) {
        const float w1a = W1[k*128 + lane],      w1b = W1[k*128 + 64 + lane];
        const float w2a = W2[k*128 + lane],      w2b = W2[k*128 + 64 + lane];
        #pragma unroll
        for (int i = 0; i < 4; ++i) {
            const float xk = __shfl(xv[i], k);
            const float zk = __shfl(zv[i], k);
            a0[i] += xk*w1a + zk*w2a;
            a1[i] += xk*w1b + zk*w2b;
        }
    }
    const float bb0 = bias1[lane]      + bias2[lane];
    const float bb1 = bias1[64 + lane] + bias2[64 + lane];
    float s0=0,q0=0,s1=0,q1=0;
    #pragma unroll
    for (int i = 0; i < 4; ++i) {
        const float v0 = a0[i] + bb0;
        const float v1 = a1[i] + bb1;
        t2[(size_t)(r0 + i)*128 + lane]      = v0;
        t2[(size_t)(r0 + i)*128 + 64 + lane] = v1;
        s0 += v0; q0 += v0*v0;
        s1 += v1; q1 += v1*v1;
    }
    // block partial row: [sum 0..127 | sumsq 128..255]
    redsh[wv][lane]        = s0;
    redsh[wv][64  + lane]  = s1;
    redsh[wv][128 + lane]  = q0;
    redsh[wv][192 + lane]  = q1;
    __syncthreads();
    {
        const int t = threadIdx.x;
        part2[blockIdx.x*256 + t] =
            redsh[0][t] + redsh[1][t] + redsh[2][t] + redsh[3][t];
    }
    __threadfence();                       // release
    __syncthreads();
    if (threadIdx.x == 0)
        amLast = (atomicAdd(cnt, 1) == (int)gridDim.x - 1);
    __syncthreads();
    if (amLast) {
        __threadfence();                   // acquire
        const int c = threadIdx.x;         // one of 256 stat columns
        const float* pp = part2 + c;
        float sum = 0.f;
        #pragma unroll 8
        for (int b = 0; b < NBLK1; ++b) sum += pp[(size_t)b*256];
        st2[c] = sum;
    }
}

// ---------------------------------------------------------------------------
// K3: out = relu(bn2(t2)), float4-vectorized (memory-bound, ~16 MB r/w)
// ---------------------------------------------------------------------------
__global__ __launch_bounds__(256) void k_bn2(
    const float* __restrict__ t2, const float* __restrict__ st,
    const float* __restrict__ g2, const float* __restrict__ b2,
    float* __restrict__ out)
{
    const int i4 = blockIdx.x * 256 + threadIdx.x;   // float4 index
    const int c4 = i4 & 31;                          // float4 within 128-col row
    const float4 sum4 = ((const float4*)st)[c4];
    const float4 sq4  = ((const float4*)(st + 128))[c4];
    const float4 g4   = ((const float4*)g2)[c4];
    const float4 bb4  = ((const float4*)b2)[c4];
    const float4 v    = ((const float4*)t2)[i4];
    const float n_inv = 1.f / NNODES;
    float4 o;
    {
        const float m = sum4.x*n_inv, va = sq4.x*n_inv - m*m;
        const float scv = rsqrtf(va + EPS)*g4.x;
        o.x = fmaxf(v.x*scv + (bb4.x - m*scv), 0.f);
    }
    {
        const float m = sum4.y*n_inv, va = sq4.y*n_inv - m*m;
        const float scv = rsqrtf(va + EPS)*g4.y;
        o.y = fmaxf(v.y*scv + (bb4.y - m*scv), 0.f);
    }
    {
        const float m = sum4.z*n_inv, va = sq4.z*n_inv - m*m;
        const float scv = rsqrtf(va + EPS)*g4.z;
        o.z = fmaxf(v.z*scv + (bb4.z - m*scv), 0.f);
    }
    {
        const float m = sum4.w*n_inv, va = sq4.w*n_inv - m*m;
        const float scv = rsqrtf(va + EPS)*g4.w;
        o.w = fmaxf(v.w*scv + (bb4.w - m*scv), 0.f);
    }
    ((float4*)out)[i4] = o;
}

extern "C" void kernel_launch(void* const* d_in, const int* in_sizes, int n_in,
                              void* d_out, int out_size, void* d_ws, size_t ws_size,
                              hipStream_t stream)
{
    const float* x     = (const float*)d_in[0];
    const float* p     = (const float*)d_in[1];
    const int*   sid   = (const int*)d_in[2];
    const int*   tid   = (const int*)d_in[3];
    // d_in[4] = B, d_in[5] = n (scalars, unused — constants hardcoded)
    const float* linsW = (const float*)d_in[6];
    const float* linsB = (const float*)d_in[7];
    const float* W1    = (const float*)d_in[8];
    const float* b1l   = (const float*)d_in[9];
    const float* W2    = (const float*)d_in[10];
    const float* b2l   = (const float*)d_in[11];
    const float* g1    = (const float*)d_in[12];
    const float* bb1   = (const float*)d_in[13];
    const float* g2    = (const float*)d_in[14];
    const float* bb2   = (const float*)d_in[15];

    float* ws    = (float*)d_ws;
    float* y1    = ws + Y1_OFF;
    float* t2    = ws + T2_OFF;
    float* part1 = ws + P1_OFF;
    float* part2 = ws + P2_OFF;
    float* st1   = ws + ST1_OFF;
    float* st2   = ws + ST2_OFF;
    int*   cnts  = (int*)(ws + CNT_OFF);

    // zero counters (+ stats for safety): harness poisons ws to 0xAA each call
    hipMemsetAsync(st1, 0, (128 + 256 + 8) * sizeof(float), stream);

    k_node  <<<NBLK1, 256, 0, stream>>>(x, p, sid, tid, linsW, linsB,
                                        y1, part1, st1, cnts + 0);
    k_fused2<<<NBLK1, 256, 0, stream>>>(x, tid, y1, st1, g1, bb1,
                                        W1, b1l, W2, b2l, t2, part2,
                                        st2, cnts + 1);
    k_bn2   <<<(NNODES*128)/(256*4), 256, 0, stream>>>(t2, st2, g2, bb2,
                                                       (float*)d_out);
}

// Round 8
// 166.175 us; speedup vs baseline: 2.7387x; 2.1707x over previous
//
#include <hip/hip_runtime.h>

// Problem constants (fixed by setup_inputs)
#define NNODES 16384      // B*n = 8*2048
#define KEDGE  16
#define EPS    1e-5f

// Workspace layout (floats) — round-4 skeleton (best known: 172 us).
// Lessons: r2 = no dense-region atomics (TCC serializes ~1/line-op);
// r6 = no cooperative grid.sync (~20us each, kills occupancy);
// r7 = no per-block __threadfence (L2 flush -> 3x latency).
#define Y1_OFF  0
#define T2_OFF  (NNODES*64)             // y1: 16384*64
#define P1_OFF  (T2_OFF + NNODES*128)   // t2: 16384*128
#define P2_OFF  (P1_OFF + 4096*128)     // part1: 4096 waves x (64 sum + 64 sumsq)
#define ST1_OFF (P2_OFF + 4096*256)     // part2: 4096 waves x (128 sum + 128 sumsq)
#define ST2_OFF (ST1_OFF + 128)

// ---------------------------------------------------------------------------
// K1: fused edge aggregation + 390x64 GEMM + per-wave BN1 partials.
// Block = 4 waves x 4 nodes/wave. launch_bounds(256,4) allows ~128 VGPRs:
// the explicit ev[16] prefetch needs the register headroom to keep 16 x-row
// gathers in flight (r1 had VGPR=116/VALUBusy=68%; r3-r7's VGPR=40 build
// serialized the gathers and stalled at 61% busy x 6.5x idle).
// ---------------------------------------------------------------------------
__global__ __launch_bounds__(256, 4) void k_node(
    const float* __restrict__ x, const float* __restrict__ p,
    const int* __restrict__ sid, const int* __restrict__ tid,
    const float* __restrict__ W, const float* __restrict__ bias,
    float* __restrict__ y1, float* __restrict__ part1)
{
    __shared__ float Ash[16][392];     // 390 used/row; 392 keeps rows 16B-aligned

    const int lane = threadIdx.x & 63;
    const int wv   = threadIdx.x >> 6;
    const int tw   = blockIdx.x * 16 + wv * 4;   // first node of this wave

    // ---- phase 1: one edge per lane (node ii = lane>>4, edge jj = lane&15)
    const int ii = lane >> 4;
    const int t1 = tw + ii;
    const int s  = sid[t1 * KEDGE + (lane & 15)];     // coalesced
    const int tn1 = tid[t1 * KEDGE];
    const float ptx = p[tn1*3+0], pty = p[tn1*3+1], ptz = p[tn1*3+2];
    const float dx = p[s*3+0] - ptx;
    const float dy = p[s*3+1] - pty;
    const float dz = p[s*3+2] - ptz;
    float pd = fmaxf(sqrtf(dx*dx + dy*dy + dz*dz), 1e-16f);

    float pr = pd;                                     // max over the 16-group
    pr = fmaxf(pr, __shfl_xor(pr, 1));
    pr = fmaxf(pr, __shfl_xor(pr, 2));
    pr = fmaxf(pr, __shfl_xor(pr, 4));
    pr = fmaxf(pr, __shfl_xor(pr, 8));
    pr *= 1.1f;

    float w = (pr - pd) * (pr - pd);
    float wsum = w;
    wsum += __shfl_xor(wsum, 1);
    wsum += __shfl_xor(wsum, 2);
    wsum += __shfl_xor(wsum, 4);
    wsum += __shfl_xor(wsum, 8);
    w /= wsum;

    const float invd = 1.f / pd;
    const float c0 = __cosf(dx * invd);   // |arg|<=1: no range reduction needed
    const float c1 = __cosf(dy * invd);
    const float c2 = __cosf(dz * invd);
    const float w0 = w * c0 * c0;
    const float w1 = w * c1 * c1;
    const float w2 = w * c2 * c2;
    const int flags = (dx > 0.f ? 1 : 0) | (dy > 0.f ? 2 : 0) | (dz > 0.f ? 4 : 0);

    // ---- phase 2: per node, PREFETCH all 16 gathers, then the FMA chain.
    #pragma unroll
    for (int i = 0; i < 4; ++i) {
        const int tn = __shfl(tn1, i * 16);
        const float xt = x[tn*64 + lane];              // lane = channel here

        float ev[KEDGE];                               // 16 gathers in flight
        #pragma unroll
        for (int j = 0; j < KEDGE; ++j) {
            const int sv = __shfl(s, i*16 + j);
            ev[j] = x[sv*64 + lane];
        }

        float A0=0,A1=0,A2=0,A3=0,A4=0,A5=0;
        float B0=0,B1=0,B2=0,B3=0,B4=0,B5=0;
        #pragma unroll
        for (int j = 0; j < KEDGE; ++j) {
            const int src = i*16 + j;
            const float q0 = __shfl(w0, src);
            const float q1 = __shfl(w1, src);
            const float q2 = __shfl(w2, src);
            const int   f  = __builtin_amdgcn_readfirstlane(__shfl(flags, src));
            const float e  = ev[j] - xt;
            if (f & 1) { A1 += q0*e; B1 += q0; } else { A0 += q0*e; B0 += q0; }
            if (f & 2) { A3 += q1*e; B3 += q1; } else { A2 += q1*e; B2 += q1; }
            if (f & 4) { A5 += q2*e; B5 += q2; } else { A4 += q2*e; B4 += q2; }
        }
        const int r = wv*4 + i;
        Ash[r][0*64+lane] = A0; Ash[r][1*64+lane] = A1; Ash[r][2*64+lane] = A2;
        Ash[r][3*64+lane] = A3; Ash[r][4*64+lane] = A4; Ash[r][5*64+lane] = A5;
        if (lane == 0) {       // B's are lane-invariant
            Ash[r][384] = B0; Ash[r][385] = B1; Ash[r][386] = B2;
            Ash[r][387] = B3; Ash[r][388] = B4; Ash[r][389] = B5;
        }
    }
    // Ash rows are wave-private; compiler's lgkmcnt wait suffices, no barrier.

    // ---- phase 3: 4-row GEMM  y = A @ [lins_W; lins_b]
    const float* Wp = W + lane;
    const int rb = wv * 4;
    float acc[4] = {0,0,0,0};
    #pragma unroll 4
    for (int k = 0; k < 384; k += 4) {
        const float4 a0 = *(const float4*)&Ash[rb+0][k];   // uniform addr -> bcast
        const float4 a1 = *(const float4*)&Ash[rb+1][k];
        const float4 a2 = *(const float4*)&Ash[rb+2][k];
        const float4 a3 = *(const float4*)&Ash[rb+3][k];
        const float wk0 = Wp[(k+0)*64];
        const float wk1 = Wp[(k+1)*64];
        const float wk2 = Wp[(k+2)*64];
        const float wk3 = Wp[(k+3)*64];
        acc[0] += a0.x*wk0 + a0.y*wk1 + a0.z*wk2 + a0.w*wk3;
        acc[1] += a1.x*wk0 + a1.y*wk1 + a1.z*wk2 + a1.w*wk3;
        acc[2] += a2.x*wk0 + a2.y*wk1 + a2.z*wk2 + a2.w*wk3;
        acc[3] += a3.x*wk0 + a3.y*wk1 + a3.z*wk2 + a3.w*wk3;
    }
    float bv[6];
    #pragma unroll
    for (int sx = 0; sx < 6; ++sx) bv[sx] = bias[sx*64 + lane];

    float sloc = 0.f, qloc = 0.f;
    #pragma unroll
    for (int i = 0; i < 4; ++i) {
        float a = acc[i];
        #pragma unroll
        for (int sx = 0; sx < 6; ++sx) a += Ash[rb+i][384+sx] * bv[sx];
        y1[(tw+i)*64 + lane] = a;
        sloc += a; qloc += a*a;
    }

    // ---- per-wave BN1 partial row (no barrier, no contention)
    const int row = blockIdx.x * 4 + wv;
    part1[row*128 + lane]      = sloc;
    part1[row*128 + 64 + lane] = qloc;
}

// ---------------------------------------------------------------------------
// Reduce 4096 x 128 BN1 partials -> st1[128].
// 64 blocks x 64 rows each; one atomicAdd per channel per block (64-way).
// ---------------------------------------------------------------------------
__global__ __launch_bounds__(256) void k_red1(
    const float* __restrict__ part, float* __restrict__ st)
{
    __shared__ float red[256];
    const int c = threadIdx.x & 127;
    const int h = threadIdx.x >> 7;            // 0/1: rows [0,32) / [32,64)
    const float* pp = part + ((size_t)blockIdx.x * 64 + h * 32) * 128 + c;
    float s = 0.f;
    #pragma unroll 8
    for (int b = 0; b < 32; ++b) s += pp[b*128];
    red[threadIdx.x] = s;
    __syncthreads();
    if (h == 0) atomicAdd(&st[c], red[c] + red[128 + c]);
}

// ---------------------------------------------------------------------------
// K2: t2 = x@lin1_W + relu(bn1(y1))@lin2_W + biases, per-wave BN2 partials.
// One wave = 4 rows; lane covers output cols {lane, lane+64}.
// launch_bounds(256,4) + 8-deep unroll: 32 W-loads batched in flight.
// ---------------------------------------------------------------------------
__global__ __launch_bounds__(256, 4) void k_fused2(
    const float* __restrict__ x, const int* __restrict__ tid,
    const float* __restrict__ y1, const float* __restrict__ stats1,
    const float* __restrict__ g1, const float* __restrict__ b1,
    const float* __restrict__ W1, const float* __restrict__ bias1,
    const float* __restrict__ W2, const float* __restrict__ bias2,
    float* __restrict__ t2, float* __restrict__ part2)
{
    const int lane = threadIdx.x & 63;
    const int wv   = threadIdx.x >> 6;
    const int r0   = (blockIdx.x * 4 + wv) * 4;

    const float mu  = stats1[lane] * (1.f / NNODES);
    const float var = stats1[64 + lane] * (1.f / NNODES) - mu*mu;
    const float sc  = rsqrtf(var + EPS) * g1[lane];
    const float sh  = b1[lane] - mu*sc;

    float xv[4], zv[4];
    #pragma unroll
    for (int i = 0; i < 4; ++i) {
        const int tn = tid[(r0 + i) * KEDGE];
        xv[i] = x[tn*64 + lane];
        const float yv = y1[(r0 + i)*64 + lane];
        zv[i] = fmaxf(yv*sc + sh, 0.f);
    }
    float a0[4] = {0,0,0,0}, a1[4] = {0,0,0,0};
    #pragma unroll 8
    for (int k = 0; k < 64; ++k) {
        const float w1a = W1[k*128 + lane],      w1b = W1[k*128 + 64 + lane];
        const float w2a = W2[k*128 + lane],      w2b = W2[k*128 + 64 + lane];
        #pragma unroll
        for (int i = 0; i < 4; ++i) {
            const float xk = __shfl(xv[i], k);
            const float zk = __shfl(zv[i], k);
            a0[i] += xk*w1a + zk*w2a;
            a1[i] += xk*w1b + zk*w2b;
        }
    }
    const float bb0 = bias1[lane]      + bias2[lane];
    const float bb1 = bias1[64 + lane] + bias2[64 + lane];
    float s0=0,q0=0,s1=0,q1=0;
    #pragma unroll
    for (int i = 0; i < 4; ++i) {
        const float v0 = a0[i] + bb0;
        const float v1 = a1[i] + bb1;
        t2[(size_t)(r0 + i)*128 + lane]      = v0;
        t2[(size_t)(r0 + i)*128 + 64 + lane] = v1;
        s0 += v0; q0 += v0*v0;
        s1 += v1; q1 += v1*v1;
    }
    // per-wave BN2 partial row (sum[0..127], sumsq[128..255])
    float* pr = part2 + ((size_t)blockIdx.x * 4 + wv) * 256;
    pr[lane]       = s0;
    pr[64 + lane]  = s1;
    pr[128 + lane] = q0;
    pr[192 + lane] = q1;
}

// ---------------------------------------------------------------------------
// Reduce 4096 x 256 BN2 partials -> st2[256].
// 64 blocks x 64 rows; each thread owns one of 256 columns; one atomic each.
// ---------------------------------------------------------------------------
__global__ __launch_bounds__(256) void k_red2(
    const float* __restrict__ part, float* __restrict__ st)
{
    const int c = threadIdx.x;
    const float* pp = part + (size_t)blockIdx.x * 64 * 256 + c;
    float s = 0.f;
    #pragma unroll 8
    for (int b = 0; b < 64; ++b) s += pp[b*256];
    atomicAdd(&st[c], s);
}

// ---------------------------------------------------------------------------
// K3: out = relu(bn2(t2)), float4-vectorized (memory-bound, ~16 MB r/w)
// ---------------------------------------------------------------------------
__global__ __launch_bounds__(256) void k_bn2(
    const float* __restrict__ t2, const float* __restrict__ st,
    const float* __restrict__ g2, const float* __restrict__ b2,
    float* __restrict__ out)
{
    const int i4 = blockIdx.x * 256 + threadIdx.x;   // float4 index
    const int c4 = i4 & 31;                          // float4 within 128-col row
    const float4 sum4 = ((const float4*)st)[c4];
    const float4 sq4  = ((const float4*)(st + 128))[c4];
    const float4 g4   = ((const float4*)g2)[c4];
    const float4 bb4  = ((const float4*)b2)[c4];
    const float4 v    = ((const float4*)t2)[i4];
    const float n_inv = 1.f / NNODES;
    float4 o;
    {
        const float m = sum4.x*n_inv, va = sq4.x*n_inv - m*m;
        const float scv = rsqrtf(va + EPS)*g4.x;
        o.x = fmaxf(v.x*scv + (bb4.x - m*scv), 0.f);
    }
    {
        const float m = sum4.y*n_inv, va = sq4.y*n_inv - m*m;
        const float scv = rsqrtf(va + EPS)*g4.y;
        o.y = fmaxf(v.y*scv + (bb4.y - m*scv), 0.f);
    }
    {
        const float m = sum4.z*n_inv, va = sq4.z*n_inv - m*m;
        const float scv = rsqrtf(va + EPS)*g4.z;
        o.z = fmaxf(v.z*scv + (bb4.z - m*scv), 0.f);
    }
    {
        const float m = sum4.w*n_inv, va = sq4.w*n_inv - m*m;
        const float scv = rsqrtf(va + EPS)*g4.w;
        o.w = fmaxf(v.w*scv + (bb4.w - m*scv), 0.f);
    }
    ((float4*)out)[i4] = o;
}

extern "C" void kernel_launch(void* const* d_in, const int* in_sizes, int n_in,
                              void* d_out, int out_size, void* d_ws, size_t ws_size,
                              hipStream_t stream)
{
    const float* x     = (const float*)d_in[0];
    const float* p     = (const float*)d_in[1];
    const int*   sid   = (const int*)d_in[2];
    const int*   tid   = (const int*)d_in[3];
    // d_in[4] = B, d_in[5] = n (scalars, unused — constants hardcoded)
    const float* linsW = (const float*)d_in[6];
    const float* linsB = (const float*)d_in[7];
    const float* W1    = (const float*)d_in[8];
    const float* b1l   = (const float*)d_in[9];
    const float* W2    = (const float*)d_in[10];
    const float* b2l   = (const float*)d_in[11];
    const float* g1    = (const float*)d_in[12];
    const float* bb1   = (const float*)d_in[13];
    const float* g2    = (const float*)d_in[14];
    const float* bb2   = (const float*)d_in[15];

    float* ws    = (float*)d_ws;
    float* y1    = ws + Y1_OFF;
    float* t2    = ws + T2_OFF;
    float* part1 = ws + P1_OFF;
    float* part2 = ws + P2_OFF;
    float* st1   = ws + ST1_OFF;
    float* st2   = ws + ST2_OFF;

    hipMemsetAsync(st1, 0, (128 + 256) * sizeof(float), stream);

    k_node  <<<NNODES/16,            256, 0, stream>>>(x, p, sid, tid, linsW,
                                                       linsB, y1, part1);
    k_red1  <<<64,                   256, 0, stream>>>(part1, st1);
    k_fused2<<<NNODES/16,            256, 0, stream>>>(x, tid, y1, st1, g1, bb1,
                                                       W1, b1l, W2, b2l, t2, part2);
    k_red2  <<<64,                   256, 0, stream>>>(part2, st2);
    k_bn2   <<<(NNODES*128)/(256*4), 256, 0, stream>>>(t2, st2, g2, bb2,
                                                       (float*)d_out);
}